// Round 17
// baseline (6416.863 us; speedup 1.0000x reference)
//
#include <hip/hip_runtime.h>

#define Bb 256
#define Tt 512
#define Dd 512
#define Hh 512
#define KTOT 1024
#define FOURH 2048

typedef __attribute__((ext_vector_type(8))) short bf16x8;
typedef __attribute__((ext_vector_type(4))) float f32x4;

__device__ __forceinline__ unsigned short f2bf(float f) {
    union { float f; unsigned u; } x; x.f = f;
    unsigned u = x.u;
    unsigned r = u + 0x7FFFu + ((u >> 16) & 1u);
    return (unsigned short)(r >> 16);
}
__device__ __forceinline__ float bf2f(unsigned short s) {
    union { unsigned u; float f; } x; x.u = ((unsigned)s) << 16;
    return x.f;
}

__device__ __forceinline__ uint4 load16_sc01(const void* p) {
    uint4 v;
    asm volatile("global_load_dwordx4 %0, %1, off sc0 sc1" : "=v"(v) : "v"(p));
    return v;
}

// Tagged int15 -> (bf16 hi, bf16 lo). Stored short s = (vq<<1)|tag,
// vq = round(h*2^14) in [-16383,16383]. Decode vq = s>>1 (arith);
// split vh = vq>>7 (8 bits), vl = vq&127 (7 bits): h = vh*2^-7 + vl*2^-14.
// Both parts exactly representable in bf16 (<=8 significant bits).
__device__ __forceinline__ void s16tag_to_bf(int s, unsigned short& bh, unsigned short& bl) {
    int vq = s >> 1;
    int vh = vq >> 7;
    int vl = vq & 127;
    union { float f; unsigned u; } a, b;
    a.f = (float)vh * 0.0078125f;            // 2^-7
    b.f = (float)vl * 6.103515625e-05f;      // 2^-14
    bh = (unsigned short)(a.u >> 16);
    bl = (unsigned short)(b.u >> 16);
}

// Transpose + split W = [Wx; Wh] into WT_hi/WT_lo [N=2048][K=1024] bf16.
__global__ void prep_w(const float* __restrict__ Wx, const float* __restrict__ Wh,
                       unsigned short* __restrict__ WT_hi, unsigned short* __restrict__ WT_lo) {
    __shared__ float tile[32][33];
    int n0 = (blockIdx.x & 63) * 32;
    int k0 = (blockIdx.x >> 6) * 32;
    int tx = threadIdx.x & 31;
    int ty = threadIdx.x >> 5;
    for (int q = 0; q < 4; ++q) {
        int k = k0 + ty + q * 8;
        int n = n0 + tx;
        float v = (k < Dd) ? Wx[(size_t)k * FOURH + n] : Wh[(size_t)(k - Dd) * FOURH + n];
        tile[ty + q * 8][tx] = v;
    }
    __syncthreads();
    for (int q = 0; q < 4; ++q) {
        int nl = ty + q * 8;
        int kl = tx;
        float v = tile[kl][nl];
        unsigned short hi = f2bf(v);
        unsigned short lo = f2bf(v - bf2f(hi));
        size_t o = (size_t)(n0 + nl) * KTOT + (size_t)(k0 + kl);
        WT_hi[o] = hi;
        WT_lo[o] = lo;
    }
}

// Init: zero ws[8M..9.5M) then, for the persist path, set the PARITY-1 h
// buffer (bytes [8M+256K, 8M+512K)) to shorts 0x0001 = (value 0, TAG 1).
// R16 BUG FIX: zero-init there was tag 0 = forged "valid" step-1 data; a
// consumer at t=1 outrunning its producer accepted init zeros as h(1).
// Tag 1 forces retry until the real tag-0 step-0 writes land.
__global__ void init_state5(char* __restrict__ ws, int persist) {
    long i = (long)blockIdx.x * blockDim.x + threadIdx.x;
    if (i < 98304) {            // 1.5 MB / 16 B
        uint4 v = (uint4){0, 0, 0, 0};
        if (persist && i >= 16384 && i < 32768)   // parity-1 h buffer
            v = (uint4){0x00010001u, 0x00010001u, 0x00010001u, 0x00010001u};
        *(uint4*)(ws + (8u << 20) + i * 16) = v;
    }
}

// ---------------- Persistent kernel: BARRIER-FREE tagged-h dataflow ---------
// 256 WGs x 512 thr (1 WG/CU). group = bx&7 (XCD heuristic). Group owns
// h-cols 64g..64g+63 for ALL rows => W slice 1 MB/XCD, L2-resident.
// slot = bx>>3: rt = slot&7 -> rows 32rt..+31; cs = slot>>3 -> 16 h-cols.
// Waves: gate=w8&3, khalf=w8>>2 (16-iter K-half loops, 88-VGPR pipelining).
// SYNC: NO barrier. h shorts carry tag ((t>>1)&1 expected at step t; writer
// stores ((t+1)>>1)&1). Consumers retry sc0sc1 loads until all tags match.
// Steady-state safety: buffer b cannot be overwritten while any cohort WG
// still reads it (overwriter needs all peers' next-step writes, which need
// their reads done). Initial condition fixed by tag-1 init of parity 1.
__global__ __launch_bounds__(512) void lstm_persist14(
    const float* __restrict__ X, const int* __restrict__ lengths,
    const unsigned short* __restrict__ WT_hi, const unsigned short* __restrict__ WT_lo,
    const float* __restrict__ bias,
    short* __restrict__ h_i16,             // [2][Bb*Hh] tagged int15 h
    float* __restrict__ out)
{
    __shared__ unsigned short HLDS[32768];   // 64 KB
    __shared__ unsigned short XLDS[32768];   // 64 KB
    __shared__ float zbuf[8][32][17];        // 17.4 KB

    const int bx = blockIdx.x;
    const int group = bx & 7;
    const int slot = bx >> 3;
    const int rt = slot & 7;
    const int cs = slot >> 3;
    const int r0 = rt * 32;
    const int j0h = group * 64 + cs * 16;
    const int tid = threadIdx.x;
    const int w8 = tid >> 6;
    const int lane = tid & 63;
    const int l15 = lane & 15;
    const int q4 = lane >> 4;
    const int klo = q4 * 8;
    const int gate = w8 & 3;
    const int khalf = w8 >> 2;

    const size_t HB = (size_t)Bb * Hh;

    // B operand: this lane's gate-column (within L2-resident 1 MB slice)
    const int colg = gate * 512 + j0h + l15;
    const size_t bbase = (size_t)colg * KTOT + (size_t)khalf * 512;
    const unsigned short* bhp = &WT_hi[bbase];
    const unsigned short* blp = &WT_lo[bbase];

    // X staging: thread stages row xr (0..31), k xk0..xk0+31
    const int xr = tid >> 4;
    const int xk0 = (tid & 15) * 32;
    const float* xbase = &X[((size_t)(r0 + xr) * Tt) * Dd + xk0];
    const int ksx = tid & 15;
    const int xmi = xr >> 4, xlr = xr & 15;

    // epilogue ownership: 1 h-element per thread (32 rows x 16 cols)
    const int er = tid >> 4;
    const int ej = tid & 15;
    const int row_g = r0 + er;
    const int col_h = j0h + ej;
    const size_t oidx = (size_t)row_g * Hh + col_h;
    int oT = lengths[row_g] - 1; if (oT < 0) oT = 0;
    const float b0 = bias[col_h], b1 = bias[512 + col_h],
                b2 = bias[1024 + col_h], b3 = bias[1536 + col_h];
    float creg = 0.f;

    // ---- stage X for t = 0 ----
    {
        const float* xp = xbase;
        float4 xv[8];
#pragma unroll
        for (int i = 0; i < 8; ++i) xv[i] = ((const float4*)xp)[i];
#pragma unroll
        for (int c2 = 0; c2 < 4; ++c2) {
            float vv[8];
            *(float4*)&vv[0] = xv[2 * c2];
            *(float4*)&vv[4] = xv[2 * c2 + 1];
            bf16x8 hv8, lv8;
#pragma unroll
            for (int e = 0; e < 8; ++e) {
                unsigned short hs = f2bf(vv[e]);
                hv8[e] = (short)hs;
                lv8[e] = (short)f2bf(vv[e] - bf2f(hs));
            }
            const int lnw = (c2 * 16 + xlr) ^ (ksx & 7);
            *(bf16x8*)&XLDS[(((0 * 2 + xmi) * 16 + ksx) * 64 + lnw) * 8] = hv8;
            *(bf16x8*)&XLDS[(((1 * 2 + xmi) * 16 + ksx) * 64 + lnw) * 8] = lv8;
        }
    }

    // ---- issue h loads for t = 0 ----
    uint4 hb[4];
    {
        const short* hp0 = h_i16;   // parity 0
#pragma unroll
        for (int it = 0; it < 4; ++it) {
            const int c = it * 512 + tid;
            const int row = c >> 6, k8 = c & 63;
            hb[it] = load16_sc01(hp0 + (size_t)(r0 + row) * Hh + k8 * 8);
        }
    }

    for (int t = 0; t < Tt; ++t) {
        const int p_r = t & 1;
        const short* hp_r = h_i16 + (size_t)p_r * HB;
        short* hp_w = h_i16 + (size_t)(p_r ^ 1) * HB;
        const unsigned expTag = (unsigned)((t >> 1) & 1);
        const unsigned tagpat = expTag ? 0x00010001u : 0u;

        // ===== retry until all granules carry this step's tag ===============
        while (true) {
            asm volatile("s_waitcnt vmcnt(0)" ::: "memory");
            __builtin_amdgcn_sched_barrier(0);
            unsigned stale = 0;
#pragma unroll
            for (int it = 0; it < 4; ++it) {
                unsigned d = ((hb[it].x ^ tagpat) | (hb[it].y ^ tagpat) |
                              (hb[it].z ^ tagpat) | (hb[it].w ^ tagpat)) & 0x00010001u;
                if (d) stale |= (1u << it);
            }
            if (!__any(stale != 0)) break;
#pragma unroll
            for (int it = 0; it < 4; ++it) {
                if (stale & (1u << it)) {
                    const int c = it * 512 + tid;
                    const int row = c >> 6, k8 = c & 63;
                    hb[it] = load16_sc01(hp_r + (size_t)(r0 + row) * Hh + k8 * 8);
                }
            }
            __builtin_amdgcn_s_sleep(4);
        }

        // ===== unpack tagged h -> HLDS (exact hi/lo split) ==================
#pragma unroll
        for (int it = 0; it < 4; ++it) {
            const int c = it * 512 + tid;
            const int row = c >> 6, k8 = c & 63;
            const int ksh = k8 >> 2, qq = k8 & 3;
            const int mi = row >> 4, lr = row & 15;
            const uint4 q = hb[it];
            const unsigned qs[4] = {q.x, q.y, q.z, q.w};
            bf16x8 ahv, alv;
#pragma unroll
            for (int e = 0; e < 4; ++e) {
                const unsigned u = qs[e];
                unsigned short bh0, bl0, bh1, bl1;
                s16tag_to_bf((int)(short)(u & 0xffffu), bh0, bl0);
                s16tag_to_bf((int)(short)(u >> 16), bh1, bl1);
                ahv[2 * e] = (short)bh0; alv[2 * e] = (short)bl0;
                ahv[2 * e + 1] = (short)bh1; alv[2 * e + 1] = (short)bl1;
            }
            const int lnw = (qq * 16 + lr) ^ (ksh & 7);
            *(bf16x8*)&HLDS[(((0 * 2 + mi) * 16 + ksh) * 64 + lnw) * 8] = ahv;
            *(bf16x8*)&HLDS[(((1 * 2 + mi) * 16 + ksh) * 64 + lnw) * 8] = alv;
        }
        __syncthreads();

        // ===== compute: split-3 MFMA, A from LDS, B from L2-resident W ======
        const unsigned short* ALDS = khalf ? HLDS : XLDS;
        f32x4 acc[2][3];
#pragma unroll
        for (int mi = 0; mi < 2; ++mi)
#pragma unroll
            for (int s = 0; s < 3; ++s)
                acc[mi][s] = (f32x4){0.f, 0.f, 0.f, 0.f};

#pragma unroll
        for (int ks = 0; ks < 16; ++ks) {
            const int kk = ks * 32 + klo;
            const bf16x8 bh = *(const bf16x8*)&bhp[kk];
            const bf16x8 bl = *(const bf16x8*)&blp[kk];
            const int lnr = lane ^ (ks & 7);
#pragma unroll
            for (int mi = 0; mi < 2; ++mi) {
                const bf16x8 ah = *(const bf16x8*)&ALDS[(((0 * 2 + mi) * 16 + ks) * 64 + lnr) * 8];
                const bf16x8 al = *(const bf16x8*)&ALDS[(((1 * 2 + mi) * 16 + ks) * 64 + lnr) * 8];
                acc[mi][0] = __builtin_amdgcn_mfma_f32_16x16x32_bf16(ah, bh, acc[mi][0], 0, 0, 0);
                acc[mi][1] = __builtin_amdgcn_mfma_f32_16x16x32_bf16(ah, bl, acc[mi][1], 0, 0, 0);
                acc[mi][2] = __builtin_amdgcn_mfma_f32_16x16x32_bf16(al, bh, acc[mi][2], 0, 0, 0);
            }
        }

        // z tiles -> LDS (C/D: col=lane&15, row=(lane>>4)*4+r)
#pragma unroll
        for (int mi = 0; mi < 2; ++mi) {
            const f32x4 z = acc[mi][0] + acc[mi][1] + acc[mi][2];
#pragma unroll
            for (int r = 0; r < 4; ++r)
                zbuf[w8][mi * 16 + q4 * 4 + r][l15] = z[r];
        }
        __syncthreads();

        // ===== epilogue: gates, state, tagged h store (no drain needed) =====
        float zi = zbuf[0][er][ej] + zbuf[4][er][ej] + b0;
        float zf = zbuf[1][er][ej] + zbuf[5][er][ej] + b1;
        float zg = zbuf[2][er][ej] + zbuf[6][er][ej] + b2;
        float zo = zbuf[3][er][ej] + zbuf[7][er][ej] + b3;
        float ig = 1.f / (1.f + expf(-zi));
        float fg = 1.f / (1.f + expf(-zf));
        float gg = tanhf(zg);
        float og = 1.f / (1.f + expf(-zo));
        float cn = fg * creg + ig * gg;
        creg = cn;
        float hn = og * tanhf(cn);
        int vi = __float2int_rn(hn * 16384.f);
        vi = vi > 16383 ? 16383 : (vi < -16383 ? -16383 : vi);
        const unsigned tagNext = (unsigned)(((t + 1) >> 1) & 1);
        short sv = (short)((vi << 1) | (int)tagNext);
        __hip_atomic_store(&hp_w[oidx], sv, __ATOMIC_RELAXED, __HIP_MEMORY_SCOPE_SYSTEM);
        if (t == oT) out[oidx] = hn;

        if (t < Tt - 1) {
            // issue next step's h loads early (overlap with X staging VALU)
            const short* hp_n = h_i16 + (size_t)((t + 1) & 1) * HB;
#pragma unroll
            for (int it = 0; it < 4; ++it) {
                const int c = it * 512 + tid;
                const int row = c >> 6, k8 = c & 63;
                hb[it] = load16_sc01(hp_n + (size_t)(r0 + row) * Hh + k8 * 8);
            }

            // stage X for t+1 (XLDS idle: all compute reads done at zbuf sync)
            const float* xp = xbase + (size_t)(t + 1) * Dd;
            float4 xv[8];
#pragma unroll
            for (int i = 0; i < 8; ++i) xv[i] = ((const float4*)xp)[i];
#pragma unroll
            for (int c2 = 0; c2 < 4; ++c2) {
                float vv[8];
                *(float4*)&vv[0] = xv[2 * c2];
                *(float4*)&vv[4] = xv[2 * c2 + 1];
                bf16x8 hv8, lv8;
#pragma unroll
                for (int e = 0; e < 8; ++e) {
                    unsigned short hs = f2bf(vv[e]);
                    hv8[e] = (short)hs;
                    lv8[e] = (short)f2bf(vv[e] - bf2f(hs));
                }
                const int lnw = (c2 * 16 + xlr) ^ (ksx & 7);
                *(bf16x8*)&XLDS[(((0 * 2 + xmi) * 16 + ksx) * 64 + lnw) * 8] = hv8;
                *(bf16x8*)&XLDS[(((1 * 2 + xmi) * 16 + ksx) * 64 + lnw) * 8] = lv8;
            }
        }
    }
}

// ---------------- Fallback: per-step kernel (round-4 proven path) ----------
__global__ __launch_bounds__(512) void lstm_step4(
    const float* __restrict__ X, const int* __restrict__ lengths,
    const unsigned short* __restrict__ WT_hi, const unsigned short* __restrict__ WT_lo,
    const float* __restrict__ bias,
    float* __restrict__ c_st,
    const unsigned short* __restrict__ h_r_hi, const unsigned short* __restrict__ h_r_lo,
    unsigned short* __restrict__ h_w_hi, unsigned short* __restrict__ h_w_lo,
    float* __restrict__ out, int t)
{
    __shared__ float zbuf[8][16][17];

    const int bx = blockIdx.x;
    const int xcd = bx & 7;
    const int rem = bx >> 3;
    const int m0 = (rem & 15) * 16;
    const int col_group = xcd * 4 + (rem >> 4);
    const int hc0 = col_group * 16;
    const int tid = threadIdx.x;
    const int w8 = tid >> 6;
    const int lane = tid & 63;
    const int gate = w8 & 3;
    const int khalf = w8 >> 2;

    f32x4 ahh = (f32x4){0,0,0,0}, ahl = (f32x4){0,0,0,0}, alh = (f32x4){0,0,0,0};

    const int colk = gate * 512 + hc0 + (lane & 15);
    const size_t bbase = (size_t)colk * KTOT;
    const int klo = (lane >> 4) * 8;
    const int row = m0 + (lane & 15);

    if (khalf == 0) {
        const float* xrow = &X[((size_t)row * Tt + t) * Dd];
        const unsigned short* bhp = &WT_hi[bbase];
        const unsigned short* blp = &WT_lo[bbase];
#pragma unroll
        for (int ks = 0; ks < 16; ++ks) {
            const int kk = ks * 32 + klo;
            const float4 v0 = *(const float4*)&xrow[kk];
            const float4 v1 = *(const float4*)&xrow[kk + 4];
            float vv[8] = {v0.x, v0.y, v0.z, v0.w, v1.x, v1.y, v1.z, v1.w};
            bf16x8 ah, al;
#pragma unroll
            for (int e = 0; e < 8; ++e) {
                unsigned short hi = f2bf(vv[e]);
                ah[e] = (short)hi;
                al[e] = (short)f2bf(vv[e] - bf2f(hi));
            }
            const bf16x8 bh = *(const bf16x8*)&bhp[kk];
            const bf16x8 bl = *(const bf16x8*)&blp[kk];
            ahh = __builtin_amdgcn_mfma_f32_16x16x32_bf16(ah, bh, ahh, 0, 0, 0);
            ahl = __builtin_amdgcn_mfma_f32_16x16x32_bf16(ah, bl, ahl, 0, 0, 0);
            alh = __builtin_amdgcn_mfma_f32_16x16x32_bf16(al, bh, alh, 0, 0, 0);
        }
    } else {
        const unsigned short* hrh = &h_r_hi[(size_t)row * Hh];
        const unsigned short* hrl = &h_r_lo[(size_t)row * Hh];
        const unsigned short* bhp = &WT_hi[bbase + 512];
        const unsigned short* blp = &WT_lo[bbase + 512];
#pragma unroll
        for (int ks = 0; ks < 16; ++ks) {
            const int kk = ks * 32 + klo;
            const bf16x8 ah = *(const bf16x8*)&hrh[kk];
            const bf16x8 al = *(const bf16x8*)&hrl[kk];
            const bf16x8 bh = *(const bf16x8*)&bhp[kk];
            const bf16x8 bl = *(const bf16x8*)&blp[kk];
            ahh = __builtin_amdgcn_mfma_f32_16x16x32_bf16(ah, bh, ahh, 0, 0, 0);
            ahl = __builtin_amdgcn_mfma_f32_16x16x32_bf16(ah, bl, ahl, 0, 0, 0);
            alh = __builtin_amdgcn_mfma_f32_16x16x32_bf16(al, bh, alh, 0, 0, 0);
        }
    }

    const f32x4 z = ahh + ahl + alh;
#pragma unroll
    for (int r = 0; r < 4; ++r)
        zbuf[w8][(lane >> 4) * 4 + r][lane & 15] = z[r];
    __syncthreads();

    if (tid < 256) {
        const int r = tid >> 4;
        const int j = tid & 15;
        const int row_g = m0 + r;
        const int col_g = hc0 + j;
        float zi = zbuf[0][r][j] + zbuf[4][r][j] + bias[col_g];
        float zf = zbuf[1][r][j] + zbuf[5][r][j] + bias[512 + col_g];
        float zg = zbuf[2][r][j] + zbuf[6][r][j] + bias[1024 + col_g];
        float zo = zbuf[3][r][j] + zbuf[7][r][j] + bias[1536 + col_g];
        float ig = 1.f / (1.f + expf(-zi));
        float fg = 1.f / (1.f + expf(-zf));
        float gg = tanhf(zg);
        float og = 1.f / (1.f + expf(-zo));
        const size_t idx = (size_t)row_g * Hh + col_g;
        float cn = fg * c_st[idx] + ig * gg;
        float hn = og * tanhf(cn);
        c_st[idx] = cn;
        unsigned short hh = f2bf(hn);
        h_w_hi[idx] = hh;
        h_w_lo[idx] = f2bf(hn - bf2f(hh));
        int len = lengths[row_g];
        int oidx = len - 1; if (oidx < 0) oidx = 0;
        if (t == oidx) out[idx] = hn;
    }
}

extern "C" void kernel_launch(void* const* d_in, const int* in_sizes, int n_in,
                              void* d_out, int out_size, void* d_ws, size_t ws_size,
                              hipStream_t stream) {
    const float* X = (const float*)d_in[0];
    const int* lengths = (const int*)d_in[1];
    const float* Wx = (const float*)d_in[2];
    const float* Wh = (const float*)d_in[3];
    const float* bias = (const float*)d_in[4];
    float* out = (float*)d_out;

    char* ws = (char*)d_ws;
    unsigned short* WT_hi = (unsigned short*)ws;                               // 0..4M
    unsigned short* WT_lo = (unsigned short*)(ws + (4u << 20));                // 4..8M
    // persistent-path buffers
    short* h_i16 = (short*)(ws + (8u << 20));                                  // 8..8.5M
    // fallback-path buffers (overlap h_i16 region; paths are exclusive)
    float* c_st = (float*)(ws + (8u << 20));
    unsigned short* h_base = (unsigned short*)(ws + (8u << 20) + (512u << 10));
    const size_t HB = (size_t)Bb * Hh;
    unsigned short* h_hi0 = h_base;
    unsigned short* h_lo0 = h_base + HB;
    unsigned short* h_hi1 = h_base + 2 * HB;
    unsigned short* h_lo1 = h_base + 3 * HB;

    const size_t NEED_PERSIST = (8u << 20) + (1536u << 10) + 32768u;
    const int can_persist = (ws_size >= NEED_PERSIST) ? 1 : 0;

    hipLaunchKernelGGL(prep_w, dim3(2048), dim3(256), 0, stream, Wx, Wh, WT_hi, WT_lo);
    hipLaunchKernelGGL(init_state5, dim3(512), dim3(256), 0, stream, ws, can_persist);

    hipError_t err = hipErrorUnknown;
    if (can_persist) {
        void* args[] = { (void*)&X, (void*)&lengths, (void*)&WT_hi, (void*)&WT_lo,
                         (void*)&bias, (void*)&h_i16, (void*)&out };
        err = hipLaunchCooperativeKernel((const void*)lstm_persist14,
                                         dim3(256), dim3(512), args, 0, stream);
    }
    if (err != hipSuccess) {
        for (int t = 0; t < Tt; ++t) {
            const bool even = (t & 1) == 0;
            hipLaunchKernelGGL(lstm_step4, dim3(512), dim3(512), 0, stream,
                               X, lengths, WT_hi, WT_lo, bias, c_st,
                               even ? h_hi0 : h_hi1, even ? h_lo0 : h_lo1,
                               even ? h_hi1 : h_hi0, even ? h_lo1 : h_lo0,
                               out, t);
        }
    }
}

// Round 18
// 6098.761 us; speedup vs baseline: 1.0522x; 1.0522x over previous
//
#include <hip/hip_runtime.h>

#define Bb 256
#define Tt 512
#define Dd 512
#define Hh 512
#define KTOT 1024
#define FOURH 2048

typedef __attribute__((ext_vector_type(8))) short bf16x8;
typedef __attribute__((ext_vector_type(4))) float f32x4;

__device__ __forceinline__ unsigned short f2bf(float f) {
    union { float f; unsigned u; } x; x.f = f;
    unsigned u = x.u;
    unsigned r = u + 0x7FFFu + ((u >> 16) & 1u);
    return (unsigned short)(r >> 16);
}
__device__ __forceinline__ float bf2f(unsigned short s) {
    union { unsigned u; float f; } x; x.u = ((unsigned)s) << 16;
    return x.f;
}

__device__ __forceinline__ uint4 load16_sc01(const void* p) {
    uint4 v;
    asm volatile("global_load_dwordx4 %0, %1, off sc0 sc1" : "=v"(v) : "v"(p));
    return v;
}

// Exact int16 -> (bf16 hi, bf16 lo): v = vh*256 + vl; h = vh*2^-7 + vl*2^-15.
// Both parts have <=8 significant bits -> exactly representable in bf16.
// Numerically verified R13/R14/R15 (absmax identical to bf16 hi/lo path).
__device__ __forceinline__ void i16_to_bf(int v, unsigned short& bh, unsigned short& bl) {
    int vh = v >> 8;
    int vl = v & 255;
    union { float f; unsigned u; } a, b;
    a.f = (float)vh * 0.0078125f;           // 2^-7
    b.f = (float)vl * 3.0517578125e-05f;    // 2^-15
    bh = (unsigned short)(a.u >> 16);
    bl = (unsigned short)(b.u >> 16);
}

// Transpose + split W = [Wx; Wh] into WT_hi/WT_lo [N=2048][K=1024] bf16.
__global__ void prep_w(const float* __restrict__ Wx, const float* __restrict__ Wh,
                       unsigned short* __restrict__ WT_hi, unsigned short* __restrict__ WT_lo) {
    __shared__ float tile[32][33];
    int n0 = (blockIdx.x & 63) * 32;
    int k0 = (blockIdx.x >> 6) * 32;
    int tx = threadIdx.x & 31;
    int ty = threadIdx.x >> 5;
    for (int q = 0; q < 4; ++q) {
        int k = k0 + ty + q * 8;
        int n = n0 + tx;
        float v = (k < Dd) ? Wx[(size_t)k * FOURH + n] : Wh[(size_t)(k - Dd) * FOURH + n];
        tile[ty + q * 8][tx] = v;
    }
    __syncthreads();
    for (int q = 0; q < 4; ++q) {
        int nl = ty + q * 8;
        int kl = tx;
        float v = tile[kl][nl];
        unsigned short hi = f2bf(v);
        unsigned short lo = f2bf(v - bf2f(hi));
        size_t o = (size_t)(n0 + nl) * KTOT + (size_t)(k0 + kl);
        WT_hi[o] = hi;
        WT_lo[o] = lo;
    }
}

// Zero ws[8M..9.5M) (h buffers / fallback state overlap) and flags at 9.5M.
__global__ void init_state3(char* __restrict__ ws, int persist) {
    long i = (long)blockIdx.x * blockDim.x + threadIdx.x;
    if (i < 98304) {            // 1.5 MB / 16 B
        *(uint4*)(ws + (8u << 20) + i * 16) = (uint4){0, 0, 0, 0};
    }
    if (persist && i < 4096) {  // 16 KB of flag lines
        ((unsigned int*)(ws + (8u << 20) + (1536u << 10)))[i] = 0u;
    }
}

// ---------------- Persistent kernel: R15 + two-phase h pipeline -------------
// 256 WGs x 512 thr (1 WG/CU). group = bx&7 (XCD heuristic). Group owns
// h-cols 64g..64g+63 for ALL rows => W slice 1 MB/XCD, L2-resident.
// slot = bx>>3: rt = slot&7 -> rows 32rt..+31; cs = slot>>3 -> 16 h-cols.
// Waves: gate=w8&3, khalf=w8>>2 (16-iter K-half loops, 88-VGPR pipelining).
// h exchange: int16 fixed (h*2^15), sc0sc1 MALL loads (R14/R15-proven).
// PIPELINE (R18): h split by k-range. Issue A(ks0-7) then B(ks8-15) loads;
// vmcnt(2) waits A only (in-order retirement); unpack A; sync; then
// khalf=0 waves run FULL X compute while khalf=1 compute ks0-7 and B flies;
// vmcnt(0); unpack B; sync; khalf=1 compute ks8-15. B-operand loaded once
// per ks (mi inner) -> no W redundancy. Barrier: R15 flag-array + X(t+1)
// staging in the poll shadow.
__global__ __launch_bounds__(512) void lstm_persist15(
    const float* __restrict__ X, const int* __restrict__ lengths,
    const unsigned short* __restrict__ WT_hi, const unsigned short* __restrict__ WT_lo,
    const float* __restrict__ bias,
    short* __restrict__ h_i16,             // [2][Bb*Hh] int16 h*2^15
    unsigned int* __restrict__ ctrl,       // flags: [8 cohorts][32 wg] x 16 uints
    float* __restrict__ out)
{
    __shared__ unsigned short HLDS[32768];   // 64 KB
    __shared__ unsigned short XLDS[32768];   // 64 KB
    __shared__ float zbuf[8][32][17];        // 17.4 KB

    const int bx = blockIdx.x;
    const int group = bx & 7;
    const int slot = bx >> 3;
    const int rt = slot & 7;
    const int cs = slot >> 3;
    const int r0 = rt * 32;
    const int j0h = group * 64 + cs * 16;
    const int tid = threadIdx.x;
    const int w8 = tid >> 6;
    const int lane = tid & 63;
    const int l15 = lane & 15;
    const int q4 = lane >> 4;
    const int klo = q4 * 8;
    const int gate = w8 & 3;
    const int khalf = w8 >> 2;

    const size_t HB = (size_t)Bb * Hh;

    // B operand: this lane's gate-column (within L2-resident 1 MB slice)
    const int colg = gate * 512 + j0h + l15;
    const size_t bbase = (size_t)colg * KTOT + (size_t)khalf * 512;
    const unsigned short* bhp = &WT_hi[bbase];
    const unsigned short* blp = &WT_lo[bbase];

    // X staging: thread stages row xr (0..31), k xk0..xk0+31
    const int xr = tid >> 4;
    const int xk0 = (tid & 15) * 32;
    const float* xbase = &X[((size_t)(r0 + xr) * Tt) * Dd + xk0];
    const int ksx = tid & 15;
    const int xmi = xr >> 4, xlr = xr & 15;

    // h granules: a = 2*tid+b (b=0,1): row = a>>5 (0..31), k8 in phase A = a&31,
    // phase B = 32+(a&31). Address hp + (r0+row)*Hh + k8*8.
    const int hrow0 = (2 * tid) >> 5;         // b=0 row
    const int hrow1 = (2 * tid + 1) >> 5;     // b=1 row
    const int hk0 = (2 * tid) & 31;
    const int hk1 = (2 * tid + 1) & 31;

    // epilogue ownership: 1 h-element per thread (32 rows x 16 cols)
    const int er = tid >> 4;
    const int ej = tid & 15;
    const int row_g = r0 + er;
    const int col_h = j0h + ej;
    const size_t oidx = (size_t)row_g * Hh + col_h;
    int oT = lengths[row_g] - 1; if (oT < 0) oT = 0;
    const float b0 = bias[col_h], b1 = bias[512 + col_h],
                b2 = bias[1024 + col_h], b3 = bias[1536 + col_h];
    float creg = 0.f;

    // flag-array barrier pointers
    const int wgIdx = group * 4 + cs;                       // 0..31 within cohort
    unsigned int* myflag = ctrl + ((size_t)(rt * 32 + wgIdx)) * 16;
    const unsigned int* flagbase = ctrl + (size_t)rt * 32 * 16;
    const unsigned int* pollp = flagbase + (size_t)(lane & 31) * 16;

    // ---- stage X for t = 0 ----
    {
        const float* xp = xbase;
        float4 xv[8];
#pragma unroll
        for (int i = 0; i < 8; ++i) xv[i] = ((const float4*)xp)[i];
#pragma unroll
        for (int c2 = 0; c2 < 4; ++c2) {
            float vv[8];
            *(float4*)&vv[0] = xv[2 * c2];
            *(float4*)&vv[4] = xv[2 * c2 + 1];
            bf16x8 hv8, lv8;
#pragma unroll
            for (int e = 0; e < 8; ++e) {
                unsigned short hs = f2bf(vv[e]);
                hv8[e] = (short)hs;
                lv8[e] = (short)f2bf(vv[e] - bf2f(hs));
            }
            const int lnw = (c2 * 16 + xlr) ^ (ksx & 7);
            *(bf16x8*)&XLDS[(((0 * 2 + xmi) * 16 + ksx) * 64 + lnw) * 8] = hv8;
            *(bf16x8*)&XLDS[(((1 * 2 + xmi) * 16 + ksx) * 64 + lnw) * 8] = lv8;
        }
    }

    for (int t = 0; t < Tt; ++t) {
        const int p_r = t & 1;
        const short* hp_r = h_i16 + (size_t)p_r * HB;
        short* hp_w = h_i16 + (size_t)(p_r ^ 1) * HB;

        // ===== issue h loads: A (ks0-7) first, then B (ks8-15) ==============
        uint4 hb[4];
        hb[0] = load16_sc01(hp_r + (size_t)(r0 + hrow0) * Hh + hk0 * 8);
        hb[1] = load16_sc01(hp_r + (size_t)(r0 + hrow1) * Hh + hk1 * 8);
        hb[2] = load16_sc01(hp_r + (size_t)(r0 + hrow0) * Hh + (32 + hk0) * 8);
        hb[3] = load16_sc01(hp_r + (size_t)(r0 + hrow1) * Hh + (32 + hk1) * 8);

        // ===== wait A only (vmcnt in-order), unpack A -> HLDS ks0-7 =========
        asm volatile("s_waitcnt vmcnt(2)" ::: "memory");
        __builtin_amdgcn_sched_barrier(0);
#pragma unroll
        for (int b = 0; b < 2; ++b) {
            const int row = b ? hrow1 : hrow0;
            const int k8 = b ? hk1 : hk0;
            const int ksh = k8 >> 2, qq = k8 & 3;
            const int mi = row >> 4, lr = row & 15;
            const uint4 q = hb[b];
            const unsigned qs[4] = {q.x, q.y, q.z, q.w};
            bf16x8 ahv, alv;
#pragma unroll
            for (int e = 0; e < 4; ++e) {
                const unsigned u = qs[e];
                unsigned short bh0, bl0, bh1, bl1;
                i16_to_bf((int)(short)(u & 0xffffu), bh0, bl0);
                i16_to_bf((int)(short)(u >> 16), bh1, bl1);
                ahv[2 * e] = (short)bh0; alv[2 * e] = (short)bl0;
                ahv[2 * e + 1] = (short)bh1; alv[2 * e + 1] = (short)bl1;
            }
            const int lnw = (qq * 16 + lr) ^ (ksh & 7);
            *(bf16x8*)&HLDS[(((0 * 2 + mi) * 16 + ksh) * 64 + lnw) * 8] = ahv;
            *(bf16x8*)&HLDS[(((1 * 2 + mi) * 16 + ksh) * 64 + lnw) * 8] = alv;
        }
        __syncthreads();

        // ===== phase 1: khalf=0 full X compute; khalf=1 ks0-7 (B in flight) =
        f32x4 acc[2][3];
#pragma unroll
        for (int mi = 0; mi < 2; ++mi)
#pragma unroll
            for (int s = 0; s < 3; ++s)
                acc[mi][s] = (f32x4){0.f, 0.f, 0.f, 0.f};

        if (khalf == 0) {
#pragma unroll
            for (int ks = 0; ks < 16; ++ks) {
                const int kk = ks * 32 + klo;
                const bf16x8 bh = *(const bf16x8*)&bhp[kk];
                const bf16x8 bl = *(const bf16x8*)&blp[kk];
                const int lnr = lane ^ (ks & 7);
#pragma unroll
                for (int mi = 0; mi < 2; ++mi) {
                    const bf16x8 ah = *(const bf16x8*)&XLDS[(((0 * 2 + mi) * 16 + ks) * 64 + lnr) * 8];
                    const bf16x8 al = *(const bf16x8*)&XLDS[(((1 * 2 + mi) * 16 + ks) * 64 + lnr) * 8];
                    acc[mi][0] = __builtin_amdgcn_mfma_f32_16x16x32_bf16(ah, bh, acc[mi][0], 0, 0, 0);
                    acc[mi][1] = __builtin_amdgcn_mfma_f32_16x16x32_bf16(ah, bl, acc[mi][1], 0, 0, 0);
                    acc[mi][2] = __builtin_amdgcn_mfma_f32_16x16x32_bf16(al, bh, acc[mi][2], 0, 0, 0);
                }
            }
            // write zbuf (read only after the pre-epilogue sync)
#pragma unroll
            for (int mi = 0; mi < 2; ++mi) {
                const f32x4 z = acc[mi][0] + acc[mi][1] + acc[mi][2];
#pragma unroll
                for (int r = 0; r < 4; ++r)
                    zbuf[w8][mi * 16 + q4 * 4 + r][l15] = z[r];
            }
        } else {
#pragma unroll
            for (int ks = 0; ks < 8; ++ks) {
                const int kk = ks * 32 + klo;
                const bf16x8 bh = *(const bf16x8*)&bhp[kk];
                const bf16x8 bl = *(const bf16x8*)&blp[kk];
                const int lnr = lane ^ (ks & 7);
#pragma unroll
                for (int mi = 0; mi < 2; ++mi) {
                    const bf16x8 ah = *(const bf16x8*)&HLDS[(((0 * 2 + mi) * 16 + ks) * 64 + lnr) * 8];
                    const bf16x8 al = *(const bf16x8*)&HLDS[(((1 * 2 + mi) * 16 + ks) * 64 + lnr) * 8];
                    acc[mi][0] = __builtin_amdgcn_mfma_f32_16x16x32_bf16(ah, bh, acc[mi][0], 0, 0, 0);
                    acc[mi][1] = __builtin_amdgcn_mfma_f32_16x16x32_bf16(ah, bl, acc[mi][1], 0, 0, 0);
                    acc[mi][2] = __builtin_amdgcn_mfma_f32_16x16x32_bf16(al, bh, acc[mi][2], 0, 0, 0);
                }
            }
        }

        // ===== wait B, unpack B -> HLDS ks8-15 ==============================
        asm volatile("s_waitcnt vmcnt(0)" ::: "memory");
        __builtin_amdgcn_sched_barrier(0);
#pragma unroll
        for (int b = 0; b < 2; ++b) {
            const int row = b ? hrow1 : hrow0;
            const int k8 = 32 + (b ? hk1 : hk0);
            const int ksh = k8 >> 2, qq = k8 & 3;
            const int mi = row >> 4, lr = row & 15;
            const uint4 q = hb[2 + b];
            const unsigned qs[4] = {q.x, q.y, q.z, q.w};
            bf16x8 ahv, alv;
#pragma unroll
            for (int e = 0; e < 4; ++e) {
                const unsigned u = qs[e];
                unsigned short bh0, bl0, bh1, bl1;
                i16_to_bf((int)(short)(u & 0xffffu), bh0, bl0);
                i16_to_bf((int)(short)(u >> 16), bh1, bl1);
                ahv[2 * e] = (short)bh0; alv[2 * e] = (short)bl0;
                ahv[2 * e + 1] = (short)bh1; alv[2 * e + 1] = (short)bl1;
            }
            const int lnw = (qq * 16 + lr) ^ (ksh & 7);
            *(bf16x8*)&HLDS[(((0 * 2 + mi) * 16 + ksh) * 64 + lnw) * 8] = ahv;
            *(bf16x8*)&HLDS[(((1 * 2 + mi) * 16 + ksh) * 64 + lnw) * 8] = alv;
        }
        __syncthreads();

        // ===== phase 2: khalf=1 ks8-15 ======================================
        if (khalf == 1) {
#pragma unroll
            for (int ks = 8; ks < 16; ++ks) {
                const int kk = ks * 32 + klo;
                const bf16x8 bh = *(const bf16x8*)&bhp[kk];
                const bf16x8 bl = *(const bf16x8*)&blp[kk];
                const int lnr = lane ^ (ks & 7);
#pragma unroll
                for (int mi = 0; mi < 2; ++mi) {
                    const bf16x8 ah = *(const bf16x8*)&HLDS[(((0 * 2 + mi) * 16 + ks) * 64 + lnr) * 8];
                    const bf16x8 al = *(const bf16x8*)&HLDS[(((1 * 2 + mi) * 16 + ks) * 64 + lnr) * 8];
                    acc[mi][0] = __builtin_amdgcn_mfma_f32_16x16x32_bf16(ah, bh, acc[mi][0], 0, 0, 0);
                    acc[mi][1] = __builtin_amdgcn_mfma_f32_16x16x32_bf16(ah, bl, acc[mi][1], 0, 0, 0);
                    acc[mi][2] = __builtin_amdgcn_mfma_f32_16x16x32_bf16(al, bh, acc[mi][2], 0, 0, 0);
                }
            }
#pragma unroll
            for (int mi = 0; mi < 2; ++mi) {
                const f32x4 z = acc[mi][0] + acc[mi][1] + acc[mi][2];
#pragma unroll
                for (int r = 0; r < 4; ++r)
                    zbuf[w8][mi * 16 + q4 * 4 + r][l15] = z[r];
            }
        }
        __syncthreads();

        // ===== epilogue ======================================================
        float zi = zbuf[0][er][ej] + zbuf[4][er][ej] + b0;
        float zf = zbuf[1][er][ej] + zbuf[5][er][ej] + b1;
        float zg = zbuf[2][er][ej] + zbuf[6][er][ej] + b2;
        float zo = zbuf[3][er][ej] + zbuf[7][er][ej] + b3;
        float ig = 1.f / (1.f + expf(-zi));
        float fg = 1.f / (1.f + expf(-zf));
        float gg = tanhf(zg);
        float og = 1.f / (1.f + expf(-zo));
        float cn = fg * creg + ig * gg;
        creg = cn;
        float hn = og * tanhf(cn);
        int vi = __float2int_rn(hn * 32768.f);
        vi = vi > 32767 ? 32767 : (vi < -32767 ? -32767 : vi);
        __hip_atomic_store(&hp_w[oidx], (short)vi, __ATOMIC_RELAXED, __HIP_MEMORY_SCOPE_SYSTEM);
        if (t == oT) out[oidx] = hn;

        // ===== flag-array barrier + X(t+1) staging in the wait shadow =======
        if (t < Tt - 1) {
            asm volatile("s_waitcnt vmcnt(0)" ::: "memory");  // h stores at MALL
            __syncthreads();
            if (tid == 0)
                __hip_atomic_store(myflag, (unsigned)(t + 1), __ATOMIC_RELAXED,
                                   __HIP_MEMORY_SCOPE_SYSTEM);

            // stage X for t+1 (XLDS idle: all compute reads done)
            {
                const float* xp = xbase + (size_t)(t + 1) * Dd;
                float4 xv[8];
#pragma unroll
                for (int i = 0; i < 8; ++i) xv[i] = ((const float4*)xp)[i];
#pragma unroll
                for (int c2 = 0; c2 < 4; ++c2) {
                    float vv[8];
                    *(float4*)&vv[0] = xv[2 * c2];
                    *(float4*)&vv[4] = xv[2 * c2 + 1];
                    bf16x8 hv8, lv8;
#pragma unroll
                    for (int e = 0; e < 8; ++e) {
                        unsigned short hs = f2bf(vv[e]);
                        hv8[e] = (short)hs;
                        lv8[e] = (short)f2bf(vv[e] - bf2f(hs));
                    }
                    const int lnw = (c2 * 16 + xlr) ^ (ksx & 7);
                    *(bf16x8*)&XLDS[(((0 * 2 + xmi) * 16 + ksx) * 64 + lnw) * 8] = hv8;
                    *(bf16x8*)&XLDS[(((1 * 2 + xmi) * 16 + ksx) * 64 + lnw) * 8] = lv8;
                }
            }

            // wave 0: one wave-wide poll of all 32 cohort flags
            if (w8 == 0) {
                while (true) {
                    unsigned v = __hip_atomic_load(pollp, __ATOMIC_RELAXED,
                                                   __HIP_MEMORY_SCOPE_SYSTEM);
                    if (__all(v >= (unsigned)(t + 1))) break;
                    __builtin_amdgcn_s_sleep(2);
                }
            }
            __syncthreads();
        }
    }
}

// ---------------- Fallback: per-step kernel (round-4 proven path) ----------
__global__ __launch_bounds__(512) void lstm_step4(
    const float* __restrict__ X, const int* __restrict__ lengths,
    const unsigned short* __restrict__ WT_hi, const unsigned short* __restrict__ WT_lo,
    const float* __restrict__ bias,
    float* __restrict__ c_st,
    const unsigned short* __restrict__ h_r_hi, const unsigned short* __restrict__ h_r_lo,
    unsigned short* __restrict__ h_w_hi, unsigned short* __restrict__ h_w_lo,
    float* __restrict__ out, int t)
{
    __shared__ float zbuf[8][16][17];

    const int bx = blockIdx.x;
    const int xcd = bx & 7;
    const int rem = bx >> 3;
    const int m0 = (rem & 15) * 16;
    const int col_group = xcd * 4 + (rem >> 4);
    const int hc0 = col_group * 16;
    const int tid = threadIdx.x;
    const int w8 = tid >> 6;
    const int lane = tid & 63;
    const int gate = w8 & 3;
    const int khalf = w8 >> 2;

    f32x4 ahh = (f32x4){0,0,0,0}, ahl = (f32x4){0,0,0,0}, alh = (f32x4){0,0,0,0};

    const int colk = gate * 512 + hc0 + (lane & 15);
    const size_t bbase = (size_t)colk * KTOT;
    const int klo = (lane >> 4) * 8;
    const int row = m0 + (lane & 15);

    if (khalf == 0) {
        const float* xrow = &X[((size_t)row * Tt + t) * Dd];
        const unsigned short* bhp = &WT_hi[bbase];
        const unsigned short* blp = &WT_lo[bbase];
#pragma unroll
        for (int ks = 0; ks < 16; ++ks) {
            const int kk = ks * 32 + klo;
            const float4 v0 = *(const float4*)&xrow[kk];
            const float4 v1 = *(const float4*)&xrow[kk + 4];
            float vv[8] = {v0.x, v0.y, v0.z, v0.w, v1.x, v1.y, v1.z, v1.w};
            bf16x8 ah, al;
#pragma unroll
            for (int e = 0; e < 8; ++e) {
                unsigned short hi = f2bf(vv[e]);
                ah[e] = (short)hi;
                al[e] = (short)f2bf(vv[e] - bf2f(hi));
            }
            const bf16x8 bh = *(const bf16x8*)&bhp[kk];
            const bf16x8 bl = *(const bf16x8*)&blp[kk];
            ahh = __builtin_amdgcn_mfma_f32_16x16x32_bf16(ah, bh, ahh, 0, 0, 0);
            ahl = __builtin_amdgcn_mfma_f32_16x16x32_bf16(ah, bl, ahl, 0, 0, 0);
            alh = __builtin_amdgcn_mfma_f32_16x16x32_bf16(al, bh, alh, 0, 0, 0);
        }
    } else {
        const unsigned short* hrh = &h_r_hi[(size_t)row * Hh];
        const unsigned short* hrl = &h_r_lo[(size_t)row * Hh];
        const unsigned short* bhp = &WT_hi[bbase + 512];
        const unsigned short* blp = &WT_lo[bbase + 512];
#pragma unroll
        for (int ks = 0; ks < 16; ++ks) {
            const int kk = ks * 32 + klo;
            const bf16x8 ah = *(const bf16x8*)&hrh[kk];
            const bf16x8 al = *(const bf16x8*)&hrl[kk];
            const bf16x8 bh = *(const bf16x8*)&bhp[kk];
            const bf16x8 bl = *(const bf16x8*)&blp[kk];
            ahh = __builtin_amdgcn_mfma_f32_16x16x32_bf16(ah, bh, ahh, 0, 0, 0);
            ahl = __builtin_amdgcn_mfma_f32_16x16x32_bf16(ah, bl, ahl, 0, 0, 0);
            alh = __builtin_amdgcn_mfma_f32_16x16x32_bf16(al, bh, alh, 0, 0, 0);
        }
    }

    const f32x4 z = ahh + ahl + alh;
#pragma unroll
    for (int r = 0; r < 4; ++r)
        zbuf[w8][(lane >> 4) * 4 + r][lane & 15] = z[r];
    __syncthreads();

    if (tid < 256) {
        const int r = tid >> 4;
        const int j = tid & 15;
        const int row_g = m0 + r;
        const int col_g = hc0 + j;
        float zi = zbuf[0][r][j] + zbuf[4][r][j] + bias[col_g];
        float zf = zbuf[1][r][j] + zbuf[5][r][j] + bias[512 + col_g];
        float zg = zbuf[2][r][j] + zbuf[6][r][j] + bias[1024 + col_g];
        float zo = zbuf[3][r][j] + zbuf[7][r][j] + bias[1536 + col_g];
        float ig = 1.f / (1.f + expf(-zi));
        float fg = 1.f / (1.f + expf(-zf));
        float gg = tanhf(zg);
        float og = 1.f / (1.f + expf(-zo));
        const size_t idx = (size_t)row_g * Hh + col_g;
        float cn = fg * c_st[idx] + ig * gg;
        float hn = og * tanhf(cn);
        c_st[idx] = cn;
        unsigned short hh = f2bf(hn);
        h_w_hi[idx] = hh;
        h_w_lo[idx] = f2bf(hn - bf2f(hh));
        int len = lengths[row_g];
        int oidx = len - 1; if (oidx < 0) oidx = 0;
        if (t == oidx) out[idx] = hn;
    }
}

extern "C" void kernel_launch(void* const* d_in, const int* in_sizes, int n_in,
                              void* d_out, int out_size, void* d_ws, size_t ws_size,
                              hipStream_t stream) {
    const float* X = (const float*)d_in[0];
    const int* lengths = (const int*)d_in[1];
    const float* Wx = (const float*)d_in[2];
    const float* Wh = (const float*)d_in[3];
    const float* bias = (const float*)d_in[4];
    float* out = (float*)d_out;

    char* ws = (char*)d_ws;
    unsigned short* WT_hi = (unsigned short*)ws;                               // 0..4M
    unsigned short* WT_lo = (unsigned short*)(ws + (4u << 20));                // 4..8M
    // persistent-path buffers
    short* h_i16 = (short*)(ws + (8u << 20));                                  // 8..8.5M
    unsigned int* ctrl = (unsigned int*)(ws + (8u << 20) + (1536u << 10));     // 9.5M..+16K
    // fallback-path buffers (overlap h_i16 region; paths are exclusive)
    float* c_st = (float*)(ws + (8u << 20));
    unsigned short* h_base = (unsigned short*)(ws + (8u << 20) + (512u << 10));
    const size_t HB = (size_t)Bb * Hh;
    unsigned short* h_hi0 = h_base;
    unsigned short* h_lo0 = h_base + HB;
    unsigned short* h_hi1 = h_base + 2 * HB;
    unsigned short* h_lo1 = h_base + 3 * HB;

    const size_t NEED_PERSIST = (8u << 20) + (1536u << 10) + 32768u;
    const int can_persist = (ws_size >= NEED_PERSIST) ? 1 : 0;

    hipLaunchKernelGGL(prep_w, dim3(2048), dim3(256), 0, stream, Wx, Wh, WT_hi, WT_lo);
    hipLaunchKernelGGL(init_state3, dim3(512), dim3(256), 0, stream, ws, can_persist);

    hipError_t err = hipErrorUnknown;
    if (can_persist) {
        void* args[] = { (void*)&X, (void*)&lengths, (void*)&WT_hi, (void*)&WT_lo,
                         (void*)&bias, (void*)&h_i16, (void*)&ctrl, (void*)&out };
        err = hipLaunchCooperativeKernel((const void*)lstm_persist15,
                                         dim3(256), dim3(512), args, 0, stream);
    }
    if (err != hipSuccess) {
        for (int t = 0; t < Tt; ++t) {
            const bool even = (t & 1) == 0;
            hipLaunchKernelGGL(lstm_step4, dim3(512), dim3(512), 0, stream,
                               X, lengths, WT_hi, WT_lo, bias, c_st,
                               even ? h_hi0 : h_hi1, even ? h_lo0 : h_lo1,
                               even ? h_hi1 : h_hi0, even ? h_lo1 : h_lo0,
                               out, t);
        }
    }
}